// Round 25
// baseline (13301.753 us; speedup 1.0000x reference)
//
#include <hip/hip_runtime.h>
#include <hip/hip_fp16.h>
#include <cstdint>
#include <cstddef>

#define B_  256
#define S_  96
#define T_  40
#define V_  256
#define E_  512
#define H_  1024
#define C_  128

typedef __attribute__((ext_vector_type(8))) short s8v;      // 8 bf16
typedef __attribute__((ext_vector_type(4))) float f4v;      // mfma acc
typedef _Float16 h8v __attribute__((ext_vector_type(8)));   // 8 fp16

__device__ __forceinline__ float sigmoidf_(float x) { return 1.0f / (1.0f + expf(-x)); }

__device__ __forceinline__ uint32_t cvtpk_bf16(float a, float b) {
  uint32_t r;
  asm("v_cvt_pk_bf16_f32 %0, %1, %2" : "=v"(r) : "v"(a), "v"(b));
  return r;
}

union U4 { uint32_t u[4]; s8v v; };

__device__ __forceinline__ void split8(const float4 a, const float4 b, s8v& hi, s8v& lo) {
  U4 H, L;
  H.u[0] = cvtpk_bf16(a.x, a.y);
  H.u[1] = cvtpk_bf16(a.z, a.w);
  H.u[2] = cvtpk_bf16(b.x, b.y);
  H.u[3] = cvtpk_bf16(b.z, b.w);
  const float r0 = a.x - __uint_as_float(H.u[0] << 16);
  const float r1 = a.y - __uint_as_float(H.u[0] & 0xffff0000u);
  const float r2 = a.z - __uint_as_float(H.u[1] << 16);
  const float r3 = a.w - __uint_as_float(H.u[1] & 0xffff0000u);
  const float r4 = b.x - __uint_as_float(H.u[2] << 16);
  const float r5 = b.y - __uint_as_float(H.u[2] & 0xffff0000u);
  const float r6 = b.z - __uint_as_float(H.u[3] << 16);
  const float r7 = b.w - __uint_as_float(H.u[3] & 0xffff0000u);
  L.u[0] = cvtpk_bf16(r0, r1);
  L.u[1] = cvtpk_bf16(r2, r3);
  L.u[2] = cvtpk_bf16(r4, r5);
  L.u[3] = cvtpk_bf16(r6, r7);
  hi = H.v; lo = L.v;
}

// =================== weight split kernels ===================
__global__ void wsplit_k(const float* __restrict__ Wf, const float* __restrict__ Wb,
                         short* __restrict__ hi, short* __restrict__ lo, int n)
{
  const int i = blockIdx.x * 256 + threadIdx.x;
  const float w = (i < n) ? Wf[i] : Wb[i - n];
  const uint32_t h = cvtpk_bf16(w, w) & 0xffffu;
  const float wh = __uint_as_float(h << 16);
  const uint32_t l = cvtpk_bf16(w - wh, w - wh) & 0xffffu;
  hi[i] = (short)h;
  lo[i] = (short)l;
}

__global__ void split_plane_k(const float* __restrict__ src, int ld_src, int col0,
                              short* __restrict__ hi, short* __restrict__ lo,
                              int ld_p, int pcol0, int total, int cols)
{
  const int i = blockIdx.x * 256 + threadIdx.x;
  if (i >= total) return;
  const int r = i / cols, c = i % cols;
  const float w = src[(size_t)r * ld_src + col0 + c];
  const uint32_t h = cvtpk_bf16(w, w) & 0xffffu;
  const float wh = __uint_as_float(h << 16);
  const uint32_t l = cvtpk_bf16(w - wh, w - wh) & 0xffffu;
  const size_t o = (size_t)r * ld_p + pcol0 + c;
  hi[o] = (short)h;
  lo[o] = (short)l;
}

// fp16 hi/lo split (for the fp16 MFMA proj)
__global__ void split_plane_h_k(const float* __restrict__ src, int ld_src, int col0,
                                __half* __restrict__ hi, __half* __restrict__ lo,
                                int ld_p, int total, int cols)
{
  const int i = blockIdx.x * 256 + threadIdx.x;
  if (i >= total) return;
  const int r = i / cols, c = i % cols;
  const float w = src[(size_t)r * ld_src + col0 + c];
  const __half h = __float2half(w);
  const __half l = __float2half(w - __half2float(h));
  const size_t o = (size_t)r * ld_p + c;
  hi[o] = h;
  lo[o] = l;
}

// =================== encoder step via MFMA bf16x3 (verified r12) ===================
struct EM {
  const int* gidx; int goff0, goff1;
  const float* Gt0; const float* Gt1;
  const float* h0; const float* h1; int ldh;
  const short* whi; const short* wlo;    // [2][3H][H]
  const float* bih0; const float* bih1;
  const float* bhh0; const float* bhh1;
  float* d0; float* d1;
  __half* e0; __half* e1; int lde;
};

__global__ __launch_bounds__(256)
void enc_mfma_k(EM g)
{
  const int fid = (blockIdx.x & 7) * 64 + (blockIdx.x >> 3);
  const int m0 = (fid & 3) * 64;
  const int r2 = fid >> 2;
  const int dir = r2 & 1;
  const int q0 = (r2 >> 1) * 16;

  __shared__ int rows[64];
  const int tid = threadIdx.x;
  if (tid < 64)
    rows[tid] = g.gidx[(size_t)(m0 + tid) * S_ + (dir ? g.goff1 : g.goff0)];
  __syncthreads();

  const int w = tid >> 6, lane = tid & 63;
  const int arow = m0 + 16 * w + (lane & 15);
  const int kc = (lane >> 4) << 3;
  const float* hsrc = dir ? g.h1 : g.h0;
  const short* whi = g.whi + (size_t)dir * (3u * H_ * H_);
  const short* wlo = g.wlo + (size_t)dir * (3u * H_ * H_);
  const float* ap = hsrc + (size_t)arow * g.ldh;
  const int wrow = q0 + (lane & 15);

  f4v acc[3];
  acc[0] = f4v{0.f, 0.f, 0.f, 0.f};
  acc[1] = f4v{0.f, 0.f, 0.f, 0.f};
  acc[2] = f4v{0.f, 0.f, 0.f, 0.f};

  float4 a0 = *(const float4*)(ap + kc);
  float4 a1 = *(const float4*)(ap + kc + 4);
  s8v bh[3], bl[3];
#pragma unroll
  for (int g3 = 0; g3 < 3; ++g3) {
    const size_t wb = (size_t)(g3 * H_ + wrow) * H_ + kc;
    bh[g3] = *(const s8v*)(whi + wb);
    bl[g3] = *(const s8v*)(wlo + wb);
  }

  for (int kb = 0; kb < 1024; kb += 32) {
    float4 na0, na1;
    s8v nbh[3], nbl[3];
    if (kb + 32 < 1024) {
      na0 = *(const float4*)(ap + kb + 32 + kc);
      na1 = *(const float4*)(ap + kb + 32 + kc + 4);
#pragma unroll
      for (int g3 = 0; g3 < 3; ++g3) {
        const size_t wb = (size_t)(g3 * H_ + wrow) * H_ + kb + 32 + kc;
        nbh[g3] = *(const s8v*)(whi + wb);
        nbl[g3] = *(const s8v*)(wlo + wb);
      }
    }
    s8v ah, al;
    split8(a0, a1, ah, al);
#pragma unroll
    for (int g3 = 0; g3 < 3; ++g3) {
      acc[g3] = __builtin_amdgcn_mfma_f32_16x16x32_bf16(ah, bh[g3], acc[g3], 0, 0, 0);
      acc[g3] = __builtin_amdgcn_mfma_f32_16x16x32_bf16(al, bh[g3], acc[g3], 0, 0, 0);
      acc[g3] = __builtin_amdgcn_mfma_f32_16x16x32_bf16(ah, bl[g3], acc[g3], 0, 0, 0);
    }
    a0 = na0; a1 = na1;
#pragma unroll
    for (int g3 = 0; g3 < 3; ++g3) { bh[g3] = nbh[g3]; bl[g3] = nbl[g3]; }
  }

  const float* bih = dir ? g.bih1 : g.bih0;
  const float* bhh = dir ? g.bhh1 : g.bhh0;
  const float* Gt = dir ? g.Gt1 : g.Gt0;
  float* dst = dir ? g.d1 : g.d0;
  __half* edst = dir ? g.e1 : g.e0;
  const int col = q0 + (lane & 15);
  const float bir = bih[col], biz = bih[H_ + col], bin = bih[2 * H_ + col];
  const float bhr = bhh[col], bhz = bhh[H_ + col], bhn = bhh[2 * H_ + col];
#pragma unroll
  for (int r = 0; r < 4; ++r) {
    const int b = m0 + 16 * w + (lane >> 4) * 4 + r;
    const float* Gr = Gt + (size_t)rows[b - m0] * (3 * H_);
    const float hold = hsrc[(size_t)b * g.ldh + col];
    const float rr = sigmoidf_(acc[0][r] + Gr[col] + bir + bhr);
    const float zz = sigmoidf_(acc[1][r] + Gr[H_ + col] + biz + bhz);
    const float nn = tanhf(Gr[2 * H_ + col] + bin + rr * (acc[2][r] + bhn));
    const float hv = (1.f - zz) * nn + zz * hold;
    dst[(size_t)b * H_ + col] = hv;
    edst[(size_t)b * g.lde + col] = __float2half(hv);
  }
}

// =================== decoder step: 12-wave MFMA, LDS-staged A ===================
struct DM {
  const float* predin;                   // ctx at row*3584 + 1024
  const float* h;
  const int* tok;
  const float* Gd;
  const short* whi; const short* wlo;    // [3H][3072]
  const float* bih; const float* bhh;
  float* d;
  float* predout;
};

__global__ __launch_bounds__(768)
void dec_mfma_k(DM g)
{
  const int fid = (blockIdx.x & 7) * 32 + (blockIdx.x >> 3);
  const int m0 = (fid & 3) * 64;
  const int q0 = (fid >> 2) * 16;
  const int tid = threadIdx.x;
  const int w = tid >> 6, lane = tid & 63;
  const int mg = w & 3;          // m-group
  const int gate = w >> 2;       // 0=r 1=z 2=n

  __shared__ short sA[2][2][64][40];     // [buf][hi/lo][row][k], pad 40 -> 2-way max
  __shared__ float eacc[4][64][16];      // r,z,nI,nH partials for epilogue

  const int srow = tid >> 2;
  const int skq = (tid & 3) << 3;
  const float* actx = g.predin + (size_t)(m0 + srow) * 3584 + 1024;
  const float* ahid = g.h + (size_t)(m0 + srow) * H_;
  auto loadA8 = [&](int kk, float4& x0, float4& x1) {
    const float* p = (kk < 2048) ? (actx + kk) : (ahid + kk - 2048);
    x0 = *(const float4*)p;
    x1 = *(const float4*)(p + 4);
  };

  const int kc = (lane >> 4) << 3;
  const int wrow = gate * H_ + q0 + (lane & 15);
  const short* whp = g.whi + (size_t)wrow * 3072 + kc;
  const short* wlp = g.wlo + (size_t)wrow * 3072 + kc;

  f4v acc0 = f4v{0.f, 0.f, 0.f, 0.f};   // r / z / nI
  f4v acc1 = acc0;                       // nH (gate 2 only)

  float4 sx0, sx1;
  if (tid < 256) loadA8(skq, sx0, sx1);
  s8v bh = *(const s8v*)whp;
  s8v bl = *(const s8v*)wlp;
  if (tid < 256) {
    s8v ah, al;
    split8(sx0, sx1, ah, al);
    *(s8v*)&sA[0][0][srow][skq] = ah;
    *(s8v*)&sA[0][1][srow][skq] = al;
  }
  __syncthreads();

  const int arowl = mg * 16 + (lane & 15);
  for (int ch = 0; ch < 96; ++ch) {
    const int buf = ch & 1;
    float4 nx0, nx1;
    if (tid < 256 && ch + 1 < 96) loadA8((ch + 1) * 32 + skq, nx0, nx1);
    s8v nbh, nbl;
    if (ch + 1 < 96) {
      nbh = *(const s8v*)(whp + (ch + 1) * 32);
      nbl = *(const s8v*)(wlp + (ch + 1) * 32);
    }
    const s8v ah = *(const s8v*)&sA[buf][0][arowl][kc];
    const s8v al = *(const s8v*)&sA[buf][1][arowl][kc];
    if (gate < 2) {
      acc0 = __builtin_amdgcn_mfma_f32_16x16x32_bf16(ah, bh, acc0, 0, 0, 0);
      acc0 = __builtin_amdgcn_mfma_f32_16x16x32_bf16(al, bh, acc0, 0, 0, 0);
      acc0 = __builtin_amdgcn_mfma_f32_16x16x32_bf16(ah, bl, acc0, 0, 0, 0);
    } else if (ch < 64) {
      acc0 = __builtin_amdgcn_mfma_f32_16x16x32_bf16(ah, bh, acc0, 0, 0, 0);
      acc0 = __builtin_amdgcn_mfma_f32_16x16x32_bf16(al, bh, acc0, 0, 0, 0);
      acc0 = __builtin_amdgcn_mfma_f32_16x16x32_bf16(ah, bl, acc0, 0, 0, 0);
    } else {
      acc1 = __builtin_amdgcn_mfma_f32_16x16x32_bf16(ah, bh, acc1, 0, 0, 0);
      acc1 = __builtin_amdgcn_mfma_f32_16x16x32_bf16(al, bh, acc1, 0, 0, 0);
      acc1 = __builtin_amdgcn_mfma_f32_16x16x32_bf16(ah, bl, acc1, 0, 0, 0);
    }
    if (tid < 256 && ch + 1 < 96) {
      s8v ah2, al2;
      split8(nx0, nx1, ah2, al2);
      *(s8v*)&sA[buf ^ 1][0][srow][skq] = ah2;
      *(s8v*)&sA[buf ^ 1][1][srow][skq] = al2;
    }
    bh = nbh; bl = nbl;
    __syncthreads();
  }

#pragma unroll
  for (int r = 0; r < 4; ++r) {
    const int lr = mg * 16 + (lane >> 4) * 4 + r;
    if (gate < 2) {
      eacc[gate][lr][lane & 15] = acc0[r];
    } else {
      eacc[2][lr][lane & 15] = acc0[r];
      eacc[3][lr][lane & 15] = acc1[r];
    }
  }
  __syncthreads();

  for (int o = tid; o < 1024; o += 768) {
    const int lr = o >> 4, lc = o & 15;
    const int b = m0 + lr, col = q0 + lc;
    const float* Gr = g.Gd + (size_t)g.tok[b] * (3 * H_);
    const float hold = g.h[(size_t)b * H_ + col];
    const float rr = sigmoidf_(eacc[0][lr][lc] + Gr[col] + g.bih[col] + g.bhh[col]);
    const float zz = sigmoidf_(eacc[1][lr][lc] + Gr[H_ + col] + g.bih[H_ + col] + g.bhh[H_ + col]);
    const float nn = tanhf(eacc[2][lr][lc] + Gr[2 * H_ + col] + g.bih[2 * H_ + col]
                           + rr * (eacc[3][lr][lc] + g.bhh[2 * H_ + col]));
    const float hv = (1.f - zz) * nn + zz * hold;
    g.d[(size_t)b * H_ + col] = hv;
    g.predout[(size_t)b * 3584 + col] = hv;
  }
}

// =================== enc_proj via fp16-split MFMA (A-once, acc[8], 3072 blocks) =========
// Block = one 16-row m-tile x half-N (512 cols); wave w covers 8 n-tiles. acc[8] halves
// the AGPR footprint (64 -> 32) so ~4-5 waves/SIMD fit, hiding L2 latency on B loads.
// The two n-halves of an m-tile are adjacent fids -> same XCD -> A stays L2-shared.
// Per-output accumulation order identical: k-chunks ascending, hi then lo.
__global__ __launch_bounds__(256)
void proj_mfma_k(const __half* __restrict__ enc, const __half* __restrict__ whi,
                 const __half* __restrict__ wlo, __half* __restrict__ proj)
{
  const int fid = (blockIdx.x & 7) * 384 + (blockIdx.x >> 3);   // 0..3071
  const int mt = fid >> 1;             // m-tile (0..1535)
  const int nh = fid & 1;              // n-half
  const int w = threadIdx.x >> 6, lane = threadIdx.x & 63;
  const int n0 = nh * 512 + w * 128;
  const int kc = (lane >> 4) << 3;
  const __half* ap = enc + (size_t)(mt * 16 + (lane & 15)) * 2048 + kc;
  const __half* bhp = whi + (size_t)(n0 + (lane & 15)) * 2048 + kc;
  const __half* blp = wlo + (size_t)(n0 + (lane & 15)) * 2048 + kc;

  f4v acc[8];
#pragma unroll
  for (int j = 0; j < 8; ++j) acc[j] = f4v{0.f, 0.f, 0.f, 0.f};

  h8v a = *(const h8v*)ap;
  for (int kb = 0; kb < 2048; kb += 32) {
    h8v na;
    if (kb + 32 < 2048) na = *(const h8v*)(ap + kb + 32);
#pragma unroll
    for (int j = 0; j < 8; ++j) {
      const h8v bh = *(const h8v*)(bhp + (size_t)j * 16 * 2048 + kb);
      const h8v bl = *(const h8v*)(blp + (size_t)j * 16 * 2048 + kb);
      acc[j] = __builtin_amdgcn_mfma_f32_16x16x32_f16(a, bh, acc[j], 0, 0, 0);
      acc[j] = __builtin_amdgcn_mfma_f32_16x16x32_f16(a, bl, acc[j], 0, 0, 0);
    }
    a = na;
  }

#pragma unroll
  for (int j = 0; j < 8; ++j)
#pragma unroll
    for (int r = 0; r < 4; ++r) {
      const int row = mt * 16 + (lane >> 4) * 4 + r;
      proj[(size_t)row * H_ + n0 + j * 16 + (lane & 15)] = __float2half(acc[j][r]);
    }
}

// =================== fused pred + q via MFMA (512 blocks, prefetch depth 2) ============
__global__ __launch_bounds__(256)
void prqa_mfma_k(const float* __restrict__ predin,
                 const short* __restrict__ fhi, const short* __restrict__ flo,
                 const float* __restrict__ bfc,
                 const float* __restrict__ hnew,
                 const short* __restrict__ qhi, const short* __restrict__ qlo,
                 float* __restrict__ out_t, float* __restrict__ qout)
{
  const int bid = blockIdx.x, tid = threadIdx.x;
  const int w = tid >> 6, lane = tid & 63;
  const int kc = (lane >> 4) << 3;
  if (bid < 256) {
    const int m0 = (bid >> 4) << 4, n0 = (bid & 15) << 4;
    const float* ap = predin + (size_t)(m0 + (lane & 15)) * 3584 + w * 896;
    const short* bhp = fhi + (size_t)(n0 + (lane & 15)) * 3584 + w * 896;
    const short* blp = flo + (size_t)(n0 + (lane & 15)) * 3584 + w * 896;
    f4v acc = f4v{0.f, 0.f, 0.f, 0.f};
    // two-slot ring (K=896 = 14 x 64)
    float4 a00 = *(const float4*)(ap + kc), a01 = *(const float4*)(ap + kc + 4);
    float4 a10 = *(const float4*)(ap + 32 + kc), a11 = *(const float4*)(ap + 32 + kc + 4);
    s8v bh0 = *(const s8v*)(bhp + kc), bl0 = *(const s8v*)(blp + kc);
    s8v bh1 = *(const s8v*)(bhp + 32 + kc), bl1 = *(const s8v*)(blp + 32 + kc);
    for (int kb = 0; kb < 896; kb += 64) {
      {
        s8v ah, al;
        split8(a00, a01, ah, al);
        acc = __builtin_amdgcn_mfma_f32_16x16x32_bf16(ah, bh0, acc, 0, 0, 0);
        acc = __builtin_amdgcn_mfma_f32_16x16x32_bf16(al, bh0, acc, 0, 0, 0);
        acc = __builtin_amdgcn_mfma_f32_16x16x32_bf16(ah, bl0, acc, 0, 0, 0);
      }
      if (kb + 64 < 896) {
        a00 = *(const float4*)(ap + kb + 64 + kc);
        a01 = *(const float4*)(ap + kb + 64 + kc + 4);
        bh0 = *(const s8v*)(bhp + kb + 64 + kc);
        bl0 = *(const s8v*)(blp + kb + 64 + kc);
      }
      {
        s8v ah, al;
        split8(a10, a11, ah, al);
        acc = __builtin_amdgcn_mfma_f32_16x16x32_bf16(ah, bh1, acc, 0, 0, 0);
        acc = __builtin_amdgcn_mfma_f32_16x16x32_bf16(al, bh1, acc, 0, 0, 0);
        acc = __builtin_amdgcn_mfma_f32_16x16x32_bf16(ah, bl1, acc, 0, 0, 0);
      }
      if (kb + 96 < 896) {
        a10 = *(const float4*)(ap + kb + 96 + kc);
        a11 = *(const float4*)(ap + kb + 96 + kc + 4);
        bh1 = *(const s8v*)(bhp + kb + 96 + kc);
        bl1 = *(const s8v*)(blp + kb + 96 + kc);
      }
    }
    __shared__ float red[4][64][4];
#pragma unroll
    for (int r = 0; r < 4; ++r) red[w][lane][r] = acc[r];
    __syncthreads();
    const int row = tid >> 4, col = tid & 15;
    const int sl = col + ((row >> 2) << 4), reg = row & 3;
    const float s = red[0][sl][reg] + red[1][sl][reg] + red[2][sl][reg] + red[3][sl][reg];
    out_t[(size_t)(m0 + row) * ((T_ - 1) * V_) + n0 + col] = s + bfc[n0 + col];
  } else {
    const int tt = (bid - 256) * 4 + w;
    const int m0 = (tt >> 6) << 4, n0 = (tt & 63) << 4;
    const float* ap = hnew + (size_t)(m0 + (lane & 15)) * H_;
    const short* bhp = qhi + (size_t)(n0 + (lane & 15)) * H_;
    const short* blp = qlo + (size_t)(n0 + (lane & 15)) * H_;
    f4v acc = f4v{0.f, 0.f, 0.f, 0.f};
    // two-slot ring (K=1024 = 16 x 64)
    float4 a00 = *(const float4*)(ap + kc), a01 = *(const float4*)(ap + kc + 4);
    float4 a10 = *(const float4*)(ap + 32 + kc), a11 = *(const float4*)(ap + 32 + kc + 4);
    s8v bh0 = *(const s8v*)(bhp + kc), bl0 = *(const s8v*)(blp + kc);
    s8v bh1 = *(const s8v*)(bhp + 32 + kc), bl1 = *(const s8v*)(blp + 32 + kc);
    for (int kb = 0; kb < 1024; kb += 64) {
      {
        s8v ah, al;
        split8(a00, a01, ah, al);
        acc = __builtin_amdgcn_mfma_f32_16x16x32_bf16(ah, bh0, acc, 0, 0, 0);
        acc = __builtin_amdgcn_mfma_f32_16x16x32_bf16(al, bh0, acc, 0, 0, 0);
        acc = __builtin_amdgcn_mfma_f32_16x16x32_bf16(ah, bl0, acc, 0, 0, 0);
      }
      if (kb + 64 < 1024) {
        a00 = *(const float4*)(ap + kb + 64 + kc);
        a01 = *(const float4*)(ap + kb + 64 + kc + 4);
        bh0 = *(const s8v*)(bhp + kb + 64 + kc);
        bl0 = *(const s8v*)(blp + kb + 64 + kc);
      }
      {
        s8v ah, al;
        split8(a10, a11, ah, al);
        acc = __builtin_amdgcn_mfma_f32_16x16x32_bf16(ah, bh1, acc, 0, 0, 0);
        acc = __builtin_amdgcn_mfma_f32_16x16x32_bf16(al, bh1, acc, 0, 0, 0);
        acc = __builtin_amdgcn_mfma_f32_16x16x32_bf16(ah, bl1, acc, 0, 0, 0);
      }
      if (kb + 96 < 1024) {
        a10 = *(const float4*)(ap + kb + 96 + kc);
        a11 = *(const float4*)(ap + kb + 96 + kc + 4);
        bh1 = *(const s8v*)(bhp + kb + 96 + kc);
        bl1 = *(const s8v*)(blp + kb + 96 + kc);
      }
    }
#pragma unroll
    for (int r = 0; r < 4; ++r)
      qout[(size_t)(m0 + (lane >> 4) * 4 + r) * H_ + n0 + (lane & 15)] = acc[r];
  }
}

// =================== fused attn: argmax + emb + scores + softmax + ctx ===================
__global__ __launch_bounds__(1024)
void attnctx_k(const float* __restrict__ out, const int* __restrict__ tgt,
               const float* __restrict__ q, const __half* __restrict__ proj,
               const float* __restrict__ va, const int* __restrict__ src,
               const float* __restrict__ dec_emb, const __half* __restrict__ enc,
               float* __restrict__ predin, int* __restrict__ tokbuf, int t)
{
  const int b = blockIdx.x, tid = threadIdx.x;
  const int lane = tid & 63, wv = tid >> 6;   // 16 waves
  __shared__ float sm[128];
  __shared__ float tr[128];
  __shared__ float rv[4];
  __shared__ int ri[4];
  __shared__ int tok_s;
  if (t == 0) {
    if (tid == 0) tok_s = tgt[(size_t)b * T_];
  } else {
    if (tid < 256) {
      float av = out[((size_t)b * (T_ - 1) + (t - 1)) * V_ + tid];
      int ai = tid;
      for (int off = 32; off; off >>= 1) {
        const float ov = __shfl_down(av, off);
        const int   oi = __shfl_down(ai, off);
        if (ov > av) { av = ov; ai = oi; }   // strict >: first-max semantics
      }
      if (lane == 0) { rv[wv] = av; ri[wv] = ai; }
    }
    __syncthreads();
    if (tid == 0) {
      float bv = rv[0]; int bi = ri[0];
      for (int w2 = 1; w2 < 4; ++w2) if (rv[w2] > bv) { bv = rv[w2]; bi = ri[w2]; }
      tok_s = bi;
    }
  }
  __syncthreads();
  const int tok = tok_s;
  if (tid == 0) tokbuf[b] = tok;
  if (tid < E_) predin[(size_t)b * 3584 + 3072 + tid] = dec_emb[(size_t)tok * E_ + tid];
  const float* qb = q + (size_t)b * H_;
  for (int s = wv * 6; s < wv * 6 + 6; ++s) {
    const __half* pb = proj + ((size_t)b * S_ + s) * H_;
    float part = 0.f;
#pragma unroll
    for (int j = 0; j < 8; ++j) {
      const int h = lane * 2 + j * 128;
      const __half2 p2 = *(const __half2*)(pb + h);
      const float2 q2 = *(const float2*)(qb + h);
      const float2 v2 = *(const float2*)(va + h);
      part += v2.x * tanhf(q2.x + __half2float(p2.x));
      part += v2.y * tanhf(q2.y + __half2float(p2.y));
    }
    for (int off = 32; off; off >>= 1) part += __shfl_down(part, off);
    if (lane == 0)
      sm[s] = (src[(size_t)b * S_ + s] == 0) ? -1.0e9f : part;
  }
  __syncthreads();
  if (tid < 128) tr[tid] = (tid < S_) ? sm[tid] : -3.0e38f;
  __syncthreads();
  for (int s2 = 64; s2 > 0; s2 >>= 1) { if (tid < s2) tr[tid] = fmaxf(tr[tid], tr[tid + s2]); __syncthreads(); }
  const float mx = tr[0];
  __syncthreads();
  if (tid < 128) tr[tid] = (tid < S_) ? expf(sm[tid] - mx) : 0.f;
  __syncthreads();
  for (int s2 = 64; s2 > 0; s2 >>= 1) { if (tid < s2) tr[tid] += tr[tid + s2]; __syncthreads(); }
  const float inv = 1.0f / tr[0];
  __syncthreads();
  if (tid < S_) sm[tid] = expf(sm[tid] - mx) * inv;
  __syncthreads();
  const int d = tid * 2;
  const __half* eb = enc + (size_t)b * S_ * (2 * H_) + d;
  float c0 = 0.f, c1 = 0.f;
  for (int s0 = 0; s0 < S_; s0 += 8) {
    __half2 v[8];
#pragma unroll
    for (int i = 0; i < 8; ++i) v[i] = *(const __half2*)(eb + (size_t)(s0 + i) * (2 * H_));
#pragma unroll
    for (int i = 0; i < 8; ++i) {
      const float w = sm[s0 + i];
      c0 += w * __half2float(v[i].x);
      c1 += w * __half2float(v[i].y);
    }
  }
  *(float2*)(predin + (size_t)b * 3584 + H_ + d) = make_float2(c0, c1);
}

// =================== generic fp32 tiled GEMM (tables / br / q0) ==============
struct GB {
  const float* A; int lda;
  const __half* Ah;
  const float* W; int ldw;
  const float* bias;
  float* C; int ldc;
  __half* Ch;
  int M, N, K, act;
  const float *hf, *hb; int ldh;
  const float *mE, *tE, *pE;
  const int *mi, *ti, *pi;
};

template<int AMODE, int CMODE>
__global__ __launch_bounds__(256)
void gemm_k(GB g0, GB g1)
{
  GB g = blockIdx.z ? g1 : g0;
  const int m0 = blockIdx.y * 64, n0 = blockIdx.x * 64;
  if (m0 >= g.M || n0 >= g.N) return;
  __shared__ float As[32][68];
  __shared__ float Ws[32][68];
  const int tid = threadIdx.x, tx = tid & 15, ty = tid >> 4;
  const int lm = tid >> 3, lk = (tid & 7) << 2;
  float acc[4][4] = {};
  float4 av[2], wv[2], av2[2], wv2[2];

  auto load_tile = [&](int k0, float4 (&AV)[2], float4 (&WV)[2]) {
#pragma unroll
    for (int i = 0; i < 2; ++i) {
      const int row = lm + i * 32;
      const int kk = k0 + lk;
      if (AMODE == 0) {
        AV[i] = *(const float4*)(g.A + (size_t)(m0 + row) * g.lda + kk);
      } else if (AMODE == 4) {
        const __half* ap = g.Ah + (size_t)(m0 + row) * g.lda + kk;
        const __half2 h0 = *(const __half2*)ap;
        const __half2 h1 = *(const __half2*)(ap + 2);
        AV[i] = make_float4(__half2float(h0.x), __half2float(h0.y),
                            __half2float(h1.x), __half2float(h1.y));
      } else {
        const int mg = m0 + row; const float* sp; size_t o;
        if (kk < 1024)      { sp = g.hf; o = (size_t)mg * g.ldh + kk; }
        else if (kk < 2048) { sp = g.hb; o = (size_t)mg * g.ldh + kk - 1024; }
        else if (kk < 2176) { sp = g.mE; o = (size_t)g.mi[mg] * C_ + kk - 2048; }
        else if (kk < 2304) { sp = g.tE; o = (size_t)g.ti[mg] * C_ + kk - 2176; }
        else                { sp = g.pE; o = (size_t)g.pi[mg] * C_ + kk - 2304; }
        AV[i] = *(const float4*)(sp + o);
      }
      WV[i] = *(const float4*)(g.W + (size_t)(n0 + row) * g.ldw + kk);
    }
  };

  load_tile(0, av, wv);
  for (int k0 = 0; k0 < g.K; k0 += 32) {
    __syncthreads();
#pragma unroll
    for (int i = 0; i < 2; ++i) {
      const int row = lm + i * 32;
      As[lk + 0][row] = av[i].x; As[lk + 1][row] = av[i].y;
      As[lk + 2][row] = av[i].z; As[lk + 3][row] = av[i].w;
      Ws[lk + 0][row] = wv[i].x; Ws[lk + 1][row] = wv[i].y;
      Ws[lk + 2][row] = wv[i].z; Ws[lk + 3][row] = wv[i].w;
    }
    __syncthreads();
    if (k0 + 32 < g.K) load_tile(k0 + 32, av2, wv2);
#pragma unroll
    for (int k = 0; k < 32; ++k) {
      const float4 a4 = *(const float4*)&As[k][ty << 2];
      const float4 b4 = *(const float4*)&Ws[k][tx << 2];
      acc[0][0] += a4.x * b4.x; acc[0][1] += a4.x * b4.y; acc[0][2] += a4.x * b4.z; acc[0][3] += a4.x * b4.w;
      acc[1][0] += a4.y * b4.x; acc[1][1] += a4.y * b4.y; acc[1][2] += a4.y * b4.z; acc[1][3] += a4.y * b4.w;
      acc[2][0] += a4.z * b4.x; acc[2][1] += a4.z * b4.y; acc[2][2] += a4.z * b4.z; acc[2][3] += a4.z * b4.w;
      acc[3][0] += a4.w * b4.x; acc[3][1] += a4.w * b4.y; acc[3][2] += a4.w * b4.z; acc[3][3] += a4.w * b4.w;
    }
#pragma unroll
    for (int i = 0; i < 2; ++i) { av[i] = av2[i]; wv[i] = wv2[i]; }
  }
  const int n = n0 + (tx << 2);
  float4 bb = make_float4(0.f, 0.f, 0.f, 0.f);
  if (g.bias) bb = *(const float4*)(g.bias + n);
#pragma unroll
  for (int i = 0; i < 4; ++i) {
    const int m = m0 + (ty << 2) + i;
    float4 v = make_float4(acc[i][0] + bb.x, acc[i][1] + bb.y, acc[i][2] + bb.z, acc[i][3] + bb.w);
    if (CMODE == 0) {
      if (g.act) { v.x = tanhf(v.x); v.y = tanhf(v.y); v.z = tanhf(v.z); v.w = tanhf(v.w); }
      *(float4*)(g.C + (size_t)m * g.ldc + n) = v;
    } else {
      __half2* cp = (__half2*)(g.Ch + (size_t)m * g.ldc + n);
      cp[0] = __floats2half2_rn(v.x, v.y);
      cp[1] = __floats2half2_rn(v.z, v.w);
    }
  }
}

// =================== misc ===================
__global__ void zero_k(float* __restrict__ p, int n)
{
  const int i = blockIdx.x * 256 + threadIdx.x;
  if (i < n) p[i] = 0.0f;
}

__global__ void sentinel_k(float* out, float v) { out[threadIdx.x] = v; }

// =================== host orchestration ===================
extern "C" void kernel_launch(void* const* d_in, const int* in_sizes, int n_in,
                              void* d_out, int out_size, void* d_ws, size_t ws_size,
                              hipStream_t stream)
{
  const int*   src        = (const int*)d_in[0];
  const int*   tgt        = (const int*)d_in[1];
  const int*   mode_idx   = (const int*)d_in[2];
  const int*   tense_idx  = (const int*)d_in[3];
  const int*   person_idx = (const int*)d_in[4];
  const float* enc_emb    = (const float*)d_in[5];
  const float* eWih_f     = (const float*)d_in[6];
  const float* eWhh_f     = (const float*)d_in[7];
  const float* ebih_f     = (const float*)d_in[8];
  const float* ebhh_f     = (const float*)d_in[9];
  const float* eWih_b     = (const float*)d_in[10];
  const float* eWhh_b     = (const float*)d_in[11];
  const float* ebih_b     = (const float*)d_in[12];
  const float* ebhh_b     = (const float*)d_in[13];
  const float* Wa         = (const float*)d_in[14];
  const float* va         = (const float*)d_in[15];
  const float* dec_emb    = (const float*)d_in[16];
  const float* dWih       = (const float*)d_in[17];
  const float* dWhh       = (const float*)d_in[18];
  const float* dbih       = (const float*)d_in[19];
  const float* dbhh       = (const float*)d_in[20];
  const float* Wfc        = (const float*)d_in[21];
  const float* bfc        = (const float*)d_in[22];
  const float* mode_E     = (const float*)d_in[23];
  const float* tense_E    = (const float*)d_in[24];
  const float* person_E   = (const float*)d_in[25];
  const float* Wbr        = (const float*)d_in[26];
  const float* bbr        = (const float*)d_in[27];
  float* out = (float*)d_out;

  // ---- workspace carve (~251 MB; proven >= 268 MB) ----
  char* base = (char*)d_ws;
  size_t off = 0;
  auto alloc = [&](size_t bytes) { char* r = base + off; off = (off + bytes + 255) & ~(size_t)255; return r; };
  __half* enc_out = (__half*)alloc(2ull * B_ * S_ * 2 * H_);   // 100.7 MB
  __half* proj    = (__half*)alloc(2ull * B_ * S_ * H_);       // 50.3 MB
  short* whh_hi = (short*)alloc(2ull * 2 * 3 * H_ * H_);       // 12.6 MB
  short* whh_lo = (short*)alloc(2ull * 2 * 3 * H_ * H_);
  short* dpl_hi = (short*)alloc(2ull * 3 * H_ * 3072);         // 18.9 MB
  short* dpl_lo = (short*)alloc(2ull * 3 * H_ * 3072);
  short* fc_hi  = (short*)alloc(2ull * V_ * 3584);             // 1.8 MB
  short* fc_lo  = (short*)alloc(2ull * V_ * 3584);
  short* qa_hi  = (short*)alloc(2ull * H_ * H_);               // 2.1 MB
  short* qa_lo  = (short*)alloc(2ull * H_ * H_);
  __half* wae_hi = (__half*)alloc(2ull * H_ * 2048);           // 4.2 MB
  __half* wae_lo = (__half*)alloc(2ull * H_ * 2048);
  float* Gi_f  = (float*)alloc(4ull * V_ * 3 * H_);
  float* Gi_b  = (float*)alloc(4ull * V_ * 3 * H_);
  float* Gd    = (float*)alloc(4ull * V_ * 3 * H_);
  float* hfA   = (float*)alloc(4ull * B_ * H_);
  float* hfB   = (float*)alloc(4ull * B_ * H_);
  float* hbA   = (float*)alloc(4ull * B_ * H_);
  float* hbB   = (float*)alloc(4ull * B_ * H_);
  float* h_d0  = (float*)alloc(4ull * B_ * H_);
  float* h_d1  = (float*)alloc(4ull * B_ * H_);
  float* q     = (float*)alloc(4ull * B_ * H_);
  float* predin = (float*)alloc(4ull * B_ * 3584);
  int*   tok   = (int*)alloc(4ull * B_);
  float* zero_buf = (float*)alloc(4ull * 1024);
  if (off > ws_size) {
    hipLaunchKernelGGL(sentinel_k, dim3(1), dim3(256), 0, stream, out,
                       1000.0f + (float)(ws_size >> 20));
    return;
  }

  hipLaunchKernelGGL(zero_k, dim3(4), dim3(256), 0, stream, zero_buf, 1024);

  // ---- weight splits ----
  {
    const int n = 3 * H_ * H_;
    hipLaunchKernelGGL(wsplit_k, dim3((2 * n) / 256), dim3(256), 0, stream,
                       eWhh_f, eWhh_b, whh_hi, whh_lo, n);
    int tot = 3 * H_ * 2048;
    hipLaunchKernelGGL(split_plane_k, dim3((tot + 255) / 256), dim3(256), 0, stream,
                       dWih, 2560, 512, dpl_hi, dpl_lo, 3072, 0, tot, 2048);
    tot = 3 * H_ * 1024;
    hipLaunchKernelGGL(split_plane_k, dim3((tot + 255) / 256), dim3(256), 0, stream,
                       dWhh, 1024, 0, dpl_hi, dpl_lo, 3072, 2048, tot, 1024);
    tot = V_ * 3584;
    hipLaunchKernelGGL(split_plane_k, dim3((tot + 255) / 256), dim3(256), 0, stream,
                       Wfc, 3584, 0, fc_hi, fc_lo, 3584, 0, tot, 3584);
    tot = H_ * 1024;
    hipLaunchKernelGGL(split_plane_k, dim3((tot + 255) / 256), dim3(256), 0, stream,
                       Wa, 3 * H_, 0, qa_hi, qa_lo, 1024, 0, tot, 1024);
    tot = H_ * 2048;
    hipLaunchKernelGGL(split_plane_h_k, dim3((tot + 255) / 256), dim3(256), 0, stream,
                       Wa, 3 * H_, 1024, wae_hi, wae_lo, 2048, tot, 2048);
  }

  GB Z{};

  // ---- token tables ----
  {
    GB t0 = Z, t1 = Z;
    t0.A = enc_emb; t0.lda = E_; t0.W = eWih_f; t0.ldw = E_;
    t0.C = Gi_f; t0.ldc = 3 * H_; t0.M = V_; t0.N = 3 * H_; t0.K = E_;
    t1 = t0; t1.W = eWih_b; t1.C = Gi_b;
    hipLaunchKernelGGL((gemm_k<0, 0>), dim3(48, 4, 2), dim3(256), 0, stream, t0, t1);
    GB t2 = Z;
    t2.A = dec_emb; t2.lda = E_; t2.W = dWih; t2.ldw = 2560;
    t2.C = Gd; t2.ldc = 3 * H_; t2.M = V_; t2.N = 3 * H_; t2.K = E_;
    hipLaunchKernelGGL((gemm_k<0, 0>), dim3(48, 4, 1), dim3(256), 0, stream, t2, t2);
  }

  // ---- encoder: 96 MFMA steps ----
  for (int t = 0; t < S_; ++t) {
    EM em{};
    em.gidx = src; em.goff0 = t; em.goff1 = S_ - 1 - t;
    em.Gt0 = Gi_f; em.Gt1 = Gi_b;
    if (t == 0) { em.h0 = zero_buf; em.h1 = zero_buf; em.ldh = 0; }
    else if (t & 1) { em.h0 = hfA; em.h1 = hbA; em.ldh = H_; }
    else            { em.h0 = hfB; em.h1 = hbB; em.ldh = H_; }
    em.whi = whh_hi; em.wlo = whh_lo;
    em.bih0 = ebih_f; em.bih1 = ebih_b; em.bhh0 = ebhh_f; em.bhh1 = ebhh_b;
    if (t & 1) { em.d0 = hfB; em.d1 = hbB; } else { em.d0 = hfA; em.d1 = hbA; }
    em.e0 = enc_out + (size_t)t * 2 * H_;
    em.e1 = enc_out + (size_t)(S_ - 1 - t) * 2 * H_ + H_;
    em.lde = S_ * 2 * H_;
    hipLaunchKernelGGL(enc_mfma_k, dim3(512), dim3(256), 0, stream, em);
  }
  float* hf_fin = hfB;   // t=95 (odd) wrote hfB/hbB
  float* hb_fin = hbB;

  // ---- enc_proj via fp16 MFMA (A-once, acc[8], 3072 blocks) ----
  hipLaunchKernelGGL(proj_mfma_k, dim3(3072), dim3(256), 0, stream,
                     enc_out, wae_hi, wae_lo, proj);

  // ---- dec_h0 ----
  {
    GB br = Z;
    br.W = Wbr; br.ldw = 2432; br.bias = bbr; br.C = h_d0; br.ldc = H_;
    br.M = B_; br.N = H_; br.K = 2432; br.act = 1;
    br.hf = hf_fin; br.hb = hb_fin; br.ldh = H_;
    br.mE = mode_E; br.tE = tense_E; br.pE = person_E;
    br.mi = mode_idx; br.ti = tense_idx; br.pi = person_idx;
    hipLaunchKernelGGL((gemm_k<2, 0>), dim3(16, 4, 1), dim3(256), 0, stream, br, br);
  }

  // ---- q(0) ----
  {
    GB qa = Z;
    qa.A = h_d0; qa.lda = H_; qa.W = Wa; qa.ldw = 3 * H_; qa.C = q; qa.ldc = H_;
    qa.M = B_; qa.N = H_; qa.K = H_;
    hipLaunchKernelGGL((gemm_k<0, 0>), dim3(16, 4, 1), dim3(256), 0, stream, qa, qa);
  }

  // ---- decoder: 39 steps x (attnctx, dec_mfma, prqa_mfma) ----
  float* hd[2] = { h_d0, h_d1 };
  for (int t = 0; t < T_ - 1; ++t) {
    hipLaunchKernelGGL(attnctx_k, dim3(B_), dim3(1024), 0, stream,
                       out, tgt, q, proj, va, src, dec_emb, enc_out, predin, tok, t);

    DM dm{};
    dm.predin = predin;
    dm.h = hd[t & 1];
    dm.tok = tok; dm.Gd = Gd;
    dm.whi = dpl_hi; dm.wlo = dpl_lo;
    dm.bih = dbih; dm.bhh = dbhh;
    dm.d = hd[(t + 1) & 1];
    dm.predout = predin;
    hipLaunchKernelGGL(dec_mfma_k, dim3(256), dim3(768), 0, stream, dm);

    hipLaunchKernelGGL(prqa_mfma_k, dim3(512), dim3(256), 0, stream,
                       predin, fc_hi, fc_lo, bfc, hd[(t + 1) & 1], qa_hi, qa_lo,
                       out + (size_t)t * V_, q);
  }
}

// Round 26
// 12686.377 us; speedup vs baseline: 1.0485x; 1.0485x over previous
//
#include <hip/hip_runtime.h>
#include <hip/hip_fp16.h>
#include <cstdint>
#include <cstddef>

#define B_  256
#define S_  96
#define T_  40
#define V_  256
#define E_  512
#define H_  1024
#define C_  128

typedef __attribute__((ext_vector_type(8))) short s8v;      // 8 bf16
typedef __attribute__((ext_vector_type(4))) float f4v;      // mfma acc
typedef _Float16 h8v __attribute__((ext_vector_type(8)));   // 8 fp16

__device__ __forceinline__ float sigmoidf_(float x) { return 1.0f / (1.0f + expf(-x)); }

__device__ __forceinline__ uint32_t cvtpk_bf16(float a, float b) {
  uint32_t r;
  asm("v_cvt_pk_bf16_f32 %0, %1, %2" : "=v"(r) : "v"(a), "v"(b));
  return r;
}

union U4 { uint32_t u[4]; s8v v; };

__device__ __forceinline__ void split8(const float4 a, const float4 b, s8v& hi, s8v& lo) {
  U4 H, L;
  H.u[0] = cvtpk_bf16(a.x, a.y);
  H.u[1] = cvtpk_bf16(a.z, a.w);
  H.u[2] = cvtpk_bf16(b.x, b.y);
  H.u[3] = cvtpk_bf16(b.z, b.w);
  const float r0 = a.x - __uint_as_float(H.u[0] << 16);
  const float r1 = a.y - __uint_as_float(H.u[0] & 0xffff0000u);
  const float r2 = a.z - __uint_as_float(H.u[1] << 16);
  const float r3 = a.w - __uint_as_float(H.u[1] & 0xffff0000u);
  const float r4 = b.x - __uint_as_float(H.u[2] << 16);
  const float r5 = b.y - __uint_as_float(H.u[2] & 0xffff0000u);
  const float r6 = b.z - __uint_as_float(H.u[3] << 16);
  const float r7 = b.w - __uint_as_float(H.u[3] & 0xffff0000u);
  L.u[0] = cvtpk_bf16(r0, r1);
  L.u[1] = cvtpk_bf16(r2, r3);
  L.u[2] = cvtpk_bf16(r4, r5);
  L.u[3] = cvtpk_bf16(r6, r7);
  hi = H.v; lo = L.v;
}

// =================== weight split kernels ===================
__global__ void wsplit_k(const float* __restrict__ Wf, const float* __restrict__ Wb,
                         short* __restrict__ hi, short* __restrict__ lo, int n)
{
  const int i = blockIdx.x * 256 + threadIdx.x;
  const float w = (i < n) ? Wf[i] : Wb[i - n];
  const uint32_t h = cvtpk_bf16(w, w) & 0xffffu;
  const float wh = __uint_as_float(h << 16);
  const uint32_t l = cvtpk_bf16(w - wh, w - wh) & 0xffffu;
  hi[i] = (short)h;
  lo[i] = (short)l;
}

__global__ void split_plane_k(const float* __restrict__ src, int ld_src, int col0,
                              short* __restrict__ hi, short* __restrict__ lo,
                              int ld_p, int pcol0, int total, int cols)
{
  const int i = blockIdx.x * 256 + threadIdx.x;
  if (i >= total) return;
  const int r = i / cols, c = i % cols;
  const float w = src[(size_t)r * ld_src + col0 + c];
  const uint32_t h = cvtpk_bf16(w, w) & 0xffffu;
  const float wh = __uint_as_float(h << 16);
  const uint32_t l = cvtpk_bf16(w - wh, w - wh) & 0xffffu;
  const size_t o = (size_t)r * ld_p + pcol0 + c;
  hi[o] = (short)h;
  lo[o] = (short)l;
}

// fp16 hi/lo split (for the fp16 MFMA proj)
__global__ void split_plane_h_k(const float* __restrict__ src, int ld_src, int col0,
                                __half* __restrict__ hi, __half* __restrict__ lo,
                                int ld_p, int total, int cols)
{
  const int i = blockIdx.x * 256 + threadIdx.x;
  if (i >= total) return;
  const int r = i / cols, c = i % cols;
  const float w = src[(size_t)r * ld_src + col0 + c];
  const __half h = __float2half(w);
  const __half l = __float2half(w - __half2float(h));
  const size_t o = (size_t)r * ld_p + c;
  hi[o] = h;
  lo[o] = l;
}

// =================== encoder step via MFMA bf16x3 (verified r12) ===================
struct EM {
  const int* gidx; int goff0, goff1;
  const float* Gt0; const float* Gt1;
  const float* h0; const float* h1; int ldh;
  const short* whi; const short* wlo;    // [2][3H][H]
  const float* bih0; const float* bih1;
  const float* bhh0; const float* bhh1;
  float* d0; float* d1;
  __half* e0; __half* e1; int lde;
};

__global__ __launch_bounds__(256)
void enc_mfma_k(EM g)
{
  const int fid = (blockIdx.x & 7) * 64 + (blockIdx.x >> 3);
  const int m0 = (fid & 3) * 64;
  const int r2 = fid >> 2;
  const int dir = r2 & 1;
  const int q0 = (r2 >> 1) * 16;

  __shared__ int rows[64];
  const int tid = threadIdx.x;
  if (tid < 64)
    rows[tid] = g.gidx[(size_t)(m0 + tid) * S_ + (dir ? g.goff1 : g.goff0)];
  __syncthreads();

  const int w = tid >> 6, lane = tid & 63;
  const int arow = m0 + 16 * w + (lane & 15);
  const int kc = (lane >> 4) << 3;
  const float* hsrc = dir ? g.h1 : g.h0;
  const short* whi = g.whi + (size_t)dir * (3u * H_ * H_);
  const short* wlo = g.wlo + (size_t)dir * (3u * H_ * H_);
  const float* ap = hsrc + (size_t)arow * g.ldh;
  const int wrow = q0 + (lane & 15);

  f4v acc[3];
  acc[0] = f4v{0.f, 0.f, 0.f, 0.f};
  acc[1] = f4v{0.f, 0.f, 0.f, 0.f};
  acc[2] = f4v{0.f, 0.f, 0.f, 0.f};

  float4 a0 = *(const float4*)(ap + kc);
  float4 a1 = *(const float4*)(ap + kc + 4);
  s8v bh[3], bl[3];
#pragma unroll
  for (int g3 = 0; g3 < 3; ++g3) {
    const size_t wb = (size_t)(g3 * H_ + wrow) * H_ + kc;
    bh[g3] = *(const s8v*)(whi + wb);
    bl[g3] = *(const s8v*)(wlo + wb);
  }

  for (int kb = 0; kb < 1024; kb += 32) {
    float4 na0, na1;
    s8v nbh[3], nbl[3];
    if (kb + 32 < 1024) {
      na0 = *(const float4*)(ap + kb + 32 + kc);
      na1 = *(const float4*)(ap + kb + 32 + kc + 4);
#pragma unroll
      for (int g3 = 0; g3 < 3; ++g3) {
        const size_t wb = (size_t)(g3 * H_ + wrow) * H_ + kb + 32 + kc;
        nbh[g3] = *(const s8v*)(whi + wb);
        nbl[g3] = *(const s8v*)(wlo + wb);
      }
    }
    s8v ah, al;
    split8(a0, a1, ah, al);
#pragma unroll
    for (int g3 = 0; g3 < 3; ++g3) {
      acc[g3] = __builtin_amdgcn_mfma_f32_16x16x32_bf16(ah, bh[g3], acc[g3], 0, 0, 0);
      acc[g3] = __builtin_amdgcn_mfma_f32_16x16x32_bf16(al, bh[g3], acc[g3], 0, 0, 0);
      acc[g3] = __builtin_amdgcn_mfma_f32_16x16x32_bf16(ah, bl[g3], acc[g3], 0, 0, 0);
    }
    a0 = na0; a1 = na1;
#pragma unroll
    for (int g3 = 0; g3 < 3; ++g3) { bh[g3] = nbh[g3]; bl[g3] = nbl[g3]; }
  }

  const float* bih = dir ? g.bih1 : g.bih0;
  const float* bhh = dir ? g.bhh1 : g.bhh0;
  const float* Gt = dir ? g.Gt1 : g.Gt0;
  float* dst = dir ? g.d1 : g.d0;
  __half* edst = dir ? g.e1 : g.e0;
  const int col = q0 + (lane & 15);
  const float bir = bih[col], biz = bih[H_ + col], bin = bih[2 * H_ + col];
  const float bhr = bhh[col], bhz = bhh[H_ + col], bhn = bhh[2 * H_ + col];
#pragma unroll
  for (int r = 0; r < 4; ++r) {
    const int b = m0 + 16 * w + (lane >> 4) * 4 + r;
    const float* Gr = Gt + (size_t)rows[b - m0] * (3 * H_);
    const float hold = hsrc[(size_t)b * g.ldh + col];
    const float rr = sigmoidf_(acc[0][r] + Gr[col] + bir + bhr);
    const float zz = sigmoidf_(acc[1][r] + Gr[H_ + col] + biz + bhz);
    const float nn = tanhf(Gr[2 * H_ + col] + bin + rr * (acc[2][r] + bhn));
    const float hv = (1.f - zz) * nn + zz * hold;
    dst[(size_t)b * H_ + col] = hv;
    edst[(size_t)b * g.lde + col] = __float2half(hv);
  }
}

// =================== decoder step: 12-wave MFMA, LDS-staged A ===================
struct DM {
  const float* predin;                   // ctx at row*3584 + 1024
  const float* h;
  const int* tok;
  const float* Gd;
  const short* whi; const short* wlo;    // [3H][3072]
  const float* bih; const float* bhh;
  float* d;
  float* predout;
};

__global__ __launch_bounds__(768)
void dec_mfma_k(DM g)
{
  const int fid = (blockIdx.x & 7) * 32 + (blockIdx.x >> 3);
  const int m0 = (fid & 3) * 64;
  const int q0 = (fid >> 2) * 16;
  const int tid = threadIdx.x;
  const int w = tid >> 6, lane = tid & 63;
  const int mg = w & 3;          // m-group
  const int gate = w >> 2;       // 0=r 1=z 2=n

  __shared__ short sA[2][2][64][40];     // [buf][hi/lo][row][k], pad 40 -> 2-way max
  __shared__ float eacc[4][64][16];      // r,z,nI,nH partials for epilogue

  const int srow = tid >> 2;
  const int skq = (tid & 3) << 3;
  const float* actx = g.predin + (size_t)(m0 + srow) * 3584 + 1024;
  const float* ahid = g.h + (size_t)(m0 + srow) * H_;
  auto loadA8 = [&](int kk, float4& x0, float4& x1) {
    const float* p = (kk < 2048) ? (actx + kk) : (ahid + kk - 2048);
    x0 = *(const float4*)p;
    x1 = *(const float4*)(p + 4);
  };

  const int kc = (lane >> 4) << 3;
  const int wrow = gate * H_ + q0 + (lane & 15);
  const short* whp = g.whi + (size_t)wrow * 3072 + kc;
  const short* wlp = g.wlo + (size_t)wrow * 3072 + kc;

  f4v acc0 = f4v{0.f, 0.f, 0.f, 0.f};   // r / z / nI
  f4v acc1 = acc0;                       // nH (gate 2 only)

  float4 sx0, sx1;
  if (tid < 256) loadA8(skq, sx0, sx1);
  s8v bh = *(const s8v*)whp;
  s8v bl = *(const s8v*)wlp;
  if (tid < 256) {
    s8v ah, al;
    split8(sx0, sx1, ah, al);
    *(s8v*)&sA[0][0][srow][skq] = ah;
    *(s8v*)&sA[0][1][srow][skq] = al;
  }
  __syncthreads();

  const int arowl = mg * 16 + (lane & 15);
  for (int ch = 0; ch < 96; ++ch) {
    const int buf = ch & 1;
    float4 nx0, nx1;
    if (tid < 256 && ch + 1 < 96) loadA8((ch + 1) * 32 + skq, nx0, nx1);
    s8v nbh, nbl;
    if (ch + 1 < 96) {
      nbh = *(const s8v*)(whp + (ch + 1) * 32);
      nbl = *(const s8v*)(wlp + (ch + 1) * 32);
    }
    const s8v ah = *(const s8v*)&sA[buf][0][arowl][kc];
    const s8v al = *(const s8v*)&sA[buf][1][arowl][kc];
    if (gate < 2) {
      acc0 = __builtin_amdgcn_mfma_f32_16x16x32_bf16(ah, bh, acc0, 0, 0, 0);
      acc0 = __builtin_amdgcn_mfma_f32_16x16x32_bf16(al, bh, acc0, 0, 0, 0);
      acc0 = __builtin_amdgcn_mfma_f32_16x16x32_bf16(ah, bl, acc0, 0, 0, 0);
    } else if (ch < 64) {
      acc0 = __builtin_amdgcn_mfma_f32_16x16x32_bf16(ah, bh, acc0, 0, 0, 0);
      acc0 = __builtin_amdgcn_mfma_f32_16x16x32_bf16(al, bh, acc0, 0, 0, 0);
      acc0 = __builtin_amdgcn_mfma_f32_16x16x32_bf16(ah, bl, acc0, 0, 0, 0);
    } else {
      acc1 = __builtin_amdgcn_mfma_f32_16x16x32_bf16(ah, bh, acc1, 0, 0, 0);
      acc1 = __builtin_amdgcn_mfma_f32_16x16x32_bf16(al, bh, acc1, 0, 0, 0);
      acc1 = __builtin_amdgcn_mfma_f32_16x16x32_bf16(ah, bl, acc1, 0, 0, 0);
    }
    if (tid < 256 && ch + 1 < 96) {
      s8v ah2, al2;
      split8(nx0, nx1, ah2, al2);
      *(s8v*)&sA[buf ^ 1][0][srow][skq] = ah2;
      *(s8v*)&sA[buf ^ 1][1][srow][skq] = al2;
    }
    bh = nbh; bl = nbl;
    __syncthreads();
  }

#pragma unroll
  for (int r = 0; r < 4; ++r) {
    const int lr = mg * 16 + (lane >> 4) * 4 + r;
    if (gate < 2) {
      eacc[gate][lr][lane & 15] = acc0[r];
    } else {
      eacc[2][lr][lane & 15] = acc0[r];
      eacc[3][lr][lane & 15] = acc1[r];
    }
  }
  __syncthreads();

  for (int o = tid; o < 1024; o += 768) {
    const int lr = o >> 4, lc = o & 15;
    const int b = m0 + lr, col = q0 + lc;
    const float* Gr = g.Gd + (size_t)g.tok[b] * (3 * H_);
    const float hold = g.h[(size_t)b * H_ + col];
    const float rr = sigmoidf_(eacc[0][lr][lc] + Gr[col] + g.bih[col] + g.bhh[col]);
    const float zz = sigmoidf_(eacc[1][lr][lc] + Gr[H_ + col] + g.bih[H_ + col] + g.bhh[H_ + col]);
    const float nn = tanhf(eacc[2][lr][lc] + Gr[2 * H_ + col] + g.bih[2 * H_ + col]
                           + rr * (eacc[3][lr][lc] + g.bhh[2 * H_ + col]));
    const float hv = (1.f - zz) * nn + zz * hold;
    g.d[(size_t)b * H_ + col] = hv;
    g.predout[(size_t)b * 3584 + col] = hv;
  }
}

// =================== enc_proj via fp16-split MFMA (m-reuse, B L1-shared) ===============
// Block = 128 m-rows x 64 n-cols; wave w owns 32 m-rows (2 A frags) x ALL 64 n-cols
// (4 n-tiles). All 4 waves stream the SAME B slice (8 KB/chunk window -> L1-shared),
// and B is amortized over 32 m-rows/wave: chip-wide B-stream drops 12.3 GB -> ~1.5-6 GB.
// 16 consecutive same-XCD fids share one m-group's A (L2). Accumulation order per
// output unchanged: k-chunks ascending, hi then lo.
__global__ __launch_bounds__(256)
void proj_mfma_k(const __half* __restrict__ enc, const __half* __restrict__ whi,
                 const __half* __restrict__ wlo, __half* __restrict__ proj)
{
  const int fid = (blockIdx.x & 7) * 384 + (blockIdx.x >> 3);   // 0..3071
  const int bm = fid >> 4;             // m-group (0..191), 128 rows
  const int bn = fid & 15;             // n-group (0..15), 64 cols
  const int w = threadIdx.x >> 6, lane = threadIdx.x & 63;
  const int n0 = bn * 64;
  const int m0 = bm * 128 + w * 32;
  const int kc = (lane >> 4) << 3;
  const __half* ap0 = enc + (size_t)(m0 + (lane & 15)) * 2048 + kc;
  const __half* ap1 = enc + (size_t)(m0 + 16 + (lane & 15)) * 2048 + kc;
  const __half* bhp = whi + (size_t)(n0 + (lane & 15)) * 2048 + kc;
  const __half* blp = wlo + (size_t)(n0 + (lane & 15)) * 2048 + kc;

  f4v acc[2][4];
#pragma unroll
  for (int i = 0; i < 2; ++i)
#pragma unroll
    for (int j = 0; j < 4; ++j) acc[i][j] = f4v{0.f, 0.f, 0.f, 0.f};

  h8v a0 = *(const h8v*)ap0;
  h8v a1 = *(const h8v*)ap1;
  for (int kb = 0; kb < 2048; kb += 32) {
    h8v na0, na1;
    if (kb + 32 < 2048) {
      na0 = *(const h8v*)(ap0 + kb + 32);
      na1 = *(const h8v*)(ap1 + kb + 32);
    }
#pragma unroll
    for (int j = 0; j < 4; ++j) {
      const h8v bh = *(const h8v*)(bhp + (size_t)j * 16 * 2048 + kb);
      const h8v bl = *(const h8v*)(blp + (size_t)j * 16 * 2048 + kb);
      acc[0][j] = __builtin_amdgcn_mfma_f32_16x16x32_f16(a0, bh, acc[0][j], 0, 0, 0);
      acc[0][j] = __builtin_amdgcn_mfma_f32_16x16x32_f16(a0, bl, acc[0][j], 0, 0, 0);
      acc[1][j] = __builtin_amdgcn_mfma_f32_16x16x32_f16(a1, bh, acc[1][j], 0, 0, 0);
      acc[1][j] = __builtin_amdgcn_mfma_f32_16x16x32_f16(a1, bl, acc[1][j], 0, 0, 0);
    }
    a0 = na0; a1 = na1;
  }

#pragma unroll
  for (int i = 0; i < 2; ++i)
#pragma unroll
    for (int j = 0; j < 4; ++j)
#pragma unroll
      for (int r = 0; r < 4; ++r) {
        const int row = m0 + i * 16 + (lane >> 4) * 4 + r;
        proj[(size_t)row * H_ + n0 + j * 16 + (lane & 15)] = __float2half(acc[i][j][r]);
      }
}

// =================== fused pred + q via MFMA (512 blocks, prefetch depth 2) ============
__global__ __launch_bounds__(256)
void prqa_mfma_k(const float* __restrict__ predin,
                 const short* __restrict__ fhi, const short* __restrict__ flo,
                 const float* __restrict__ bfc,
                 const float* __restrict__ hnew,
                 const short* __restrict__ qhi, const short* __restrict__ qlo,
                 float* __restrict__ out_t, float* __restrict__ qout)
{
  const int bid = blockIdx.x, tid = threadIdx.x;
  const int w = tid >> 6, lane = tid & 63;
  const int kc = (lane >> 4) << 3;
  if (bid < 256) {
    const int m0 = (bid >> 4) << 4, n0 = (bid & 15) << 4;
    const float* ap = predin + (size_t)(m0 + (lane & 15)) * 3584 + w * 896;
    const short* bhp = fhi + (size_t)(n0 + (lane & 15)) * 3584 + w * 896;
    const short* blp = flo + (size_t)(n0 + (lane & 15)) * 3584 + w * 896;
    f4v acc = f4v{0.f, 0.f, 0.f, 0.f};
    // two-slot ring (K=896 = 14 x 64)
    float4 a00 = *(const float4*)(ap + kc), a01 = *(const float4*)(ap + kc + 4);
    float4 a10 = *(const float4*)(ap + 32 + kc), a11 = *(const float4*)(ap + 32 + kc + 4);
    s8v bh0 = *(const s8v*)(bhp + kc), bl0 = *(const s8v*)(blp + kc);
    s8v bh1 = *(const s8v*)(bhp + 32 + kc), bl1 = *(const s8v*)(blp + 32 + kc);
    for (int kb = 0; kb < 896; kb += 64) {
      {
        s8v ah, al;
        split8(a00, a01, ah, al);
        acc = __builtin_amdgcn_mfma_f32_16x16x32_bf16(ah, bh0, acc, 0, 0, 0);
        acc = __builtin_amdgcn_mfma_f32_16x16x32_bf16(al, bh0, acc, 0, 0, 0);
        acc = __builtin_amdgcn_mfma_f32_16x16x32_bf16(ah, bl0, acc, 0, 0, 0);
      }
      if (kb + 64 < 896) {
        a00 = *(const float4*)(ap + kb + 64 + kc);
        a01 = *(const float4*)(ap + kb + 64 + kc + 4);
        bh0 = *(const s8v*)(bhp + kb + 64 + kc);
        bl0 = *(const s8v*)(blp + kb + 64 + kc);
      }
      {
        s8v ah, al;
        split8(a10, a11, ah, al);
        acc = __builtin_amdgcn_mfma_f32_16x16x32_bf16(ah, bh1, acc, 0, 0, 0);
        acc = __builtin_amdgcn_mfma_f32_16x16x32_bf16(al, bh1, acc, 0, 0, 0);
        acc = __builtin_amdgcn_mfma_f32_16x16x32_bf16(ah, bl1, acc, 0, 0, 0);
      }
      if (kb + 96 < 896) {
        a10 = *(const float4*)(ap + kb + 96 + kc);
        a11 = *(const float4*)(ap + kb + 96 + kc + 4);
        bh1 = *(const s8v*)(bhp + kb + 96 + kc);
        bl1 = *(const s8v*)(blp + kb + 96 + kc);
      }
    }
    __shared__ float red[4][64][4];
#pragma unroll
    for (int r = 0; r < 4; ++r) red[w][lane][r] = acc[r];
    __syncthreads();
    const int row = tid >> 4, col = tid & 15;
    const int sl = col + ((row >> 2) << 4), reg = row & 3;
    const float s = red[0][sl][reg] + red[1][sl][reg] + red[2][sl][reg] + red[3][sl][reg];
    out_t[(size_t)(m0 + row) * ((T_ - 1) * V_) + n0 + col] = s + bfc[n0 + col];
  } else {
    const int tt = (bid - 256) * 4 + w;
    const int m0 = (tt >> 6) << 4, n0 = (tt & 63) << 4;
    const float* ap = hnew + (size_t)(m0 + (lane & 15)) * H_;
    const short* bhp = qhi + (size_t)(n0 + (lane & 15)) * H_;
    const short* blp = qlo + (size_t)(n0 + (lane & 15)) * H_;
    f4v acc = f4v{0.f, 0.f, 0.f, 0.f};
    // two-slot ring (K=1024 = 16 x 64)
    float4 a00 = *(const float4*)(ap + kc), a01 = *(const float4*)(ap + kc + 4);
    float4 a10 = *(const float4*)(ap + 32 + kc), a11 = *(const float4*)(ap + 32 + kc + 4);
    s8v bh0 = *(const s8v*)(bhp + kc), bl0 = *(const s8v*)(blp + kc);
    s8v bh1 = *(const s8v*)(bhp + 32 + kc), bl1 = *(const s8v*)(blp + 32 + kc);
    for (int kb = 0; kb < 1024; kb += 64) {
      {
        s8v ah, al;
        split8(a00, a01, ah, al);
        acc = __builtin_amdgcn_mfma_f32_16x16x32_bf16(ah, bh0, acc, 0, 0, 0);
        acc = __builtin_amdgcn_mfma_f32_16x16x32_bf16(al, bh0, acc, 0, 0, 0);
        acc = __builtin_amdgcn_mfma_f32_16x16x32_bf16(ah, bl0, acc, 0, 0, 0);
      }
      if (kb + 64 < 1024) {
        a00 = *(const float4*)(ap + kb + 64 + kc);
        a01 = *(const float4*)(ap + kb + 64 + kc + 4);
        bh0 = *(const s8v*)(bhp + kb + 64 + kc);
        bl0 = *(const s8v*)(blp + kb + 64 + kc);
      }
      {
        s8v ah, al;
        split8(a10, a11, ah, al);
        acc = __builtin_amdgcn_mfma_f32_16x16x32_bf16(ah, bh1, acc, 0, 0, 0);
        acc = __builtin_amdgcn_mfma_f32_16x16x32_bf16(al, bh1, acc, 0, 0, 0);
        acc = __builtin_amdgcn_mfma_f32_16x16x32_bf16(ah, bl1, acc, 0, 0, 0);
      }
      if (kb + 96 < 1024) {
        a10 = *(const float4*)(ap + kb + 96 + kc);
        a11 = *(const float4*)(ap + kb + 96 + kc + 4);
        bh1 = *(const s8v*)(bhp + kb + 96 + kc);
        bl1 = *(const s8v*)(blp + kb + 96 + kc);
      }
    }
#pragma unroll
    for (int r = 0; r < 4; ++r)
      qout[(size_t)(m0 + (lane >> 4) * 4 + r) * H_ + n0 + (lane & 15)] = acc[r];
  }
}

// =================== fused attn: argmax + emb + scores + softmax + ctx ===================
__global__ __launch_bounds__(1024)
void attnctx_k(const float* __restrict__ out, const int* __restrict__ tgt,
               const float* __restrict__ q, const __half* __restrict__ proj,
               const float* __restrict__ va, const int* __restrict__ src,
               const float* __restrict__ dec_emb, const __half* __restrict__ enc,
               float* __restrict__ predin, int* __restrict__ tokbuf, int t)
{
  const int b = blockIdx.x, tid = threadIdx.x;
  const int lane = tid & 63, wv = tid >> 6;   // 16 waves
  __shared__ float sm[128];
  __shared__ float tr[128];
  __shared__ float rv[4];
  __shared__ int ri[4];
  __shared__ int tok_s;
  if (t == 0) {
    if (tid == 0) tok_s = tgt[(size_t)b * T_];
  } else {
    if (tid < 256) {
      float av = out[((size_t)b * (T_ - 1) + (t - 1)) * V_ + tid];
      int ai = tid;
      for (int off = 32; off; off >>= 1) {
        const float ov = __shfl_down(av, off);
        const int   oi = __shfl_down(ai, off);
        if (ov > av) { av = ov; ai = oi; }   // strict >: first-max semantics
      }
      if (lane == 0) { rv[wv] = av; ri[wv] = ai; }
    }
    __syncthreads();
    if (tid == 0) {
      float bv = rv[0]; int bi = ri[0];
      for (int w2 = 1; w2 < 4; ++w2) if (rv[w2] > bv) { bv = rv[w2]; bi = ri[w2]; }
      tok_s = bi;
    }
  }
  __syncthreads();
  const int tok = tok_s;
  if (tid == 0) tokbuf[b] = tok;
  if (tid < E_) predin[(size_t)b * 3584 + 3072 + tid] = dec_emb[(size_t)tok * E_ + tid];
  const float* qb = q + (size_t)b * H_;
  for (int s = wv * 6; s < wv * 6 + 6; ++s) {
    const __half* pb = proj + ((size_t)b * S_ + s) * H_;
    float part = 0.f;
#pragma unroll
    for (int j = 0; j < 8; ++j) {
      const int h = lane * 2 + j * 128;
      const __half2 p2 = *(const __half2*)(pb + h);
      const float2 q2 = *(const float2*)(qb + h);
      const float2 v2 = *(const float2*)(va + h);
      part += v2.x * tanhf(q2.x + __half2float(p2.x));
      part += v2.y * tanhf(q2.y + __half2float(p2.y));
    }
    for (int off = 32; off; off >>= 1) part += __shfl_down(part, off);
    if (lane == 0)
      sm[s] = (src[(size_t)b * S_ + s] == 0) ? -1.0e9f : part;
  }
  __syncthreads();
  if (tid < 128) tr[tid] = (tid < S_) ? sm[tid] : -3.0e38f;
  __syncthreads();
  for (int s2 = 64; s2 > 0; s2 >>= 1) { if (tid < s2) tr[tid] = fmaxf(tr[tid], tr[tid + s2]); __syncthreads(); }
  const float mx = tr[0];
  __syncthreads();
  if (tid < 128) tr[tid] = (tid < S_) ? expf(sm[tid] - mx) : 0.f;
  __syncthreads();
  for (int s2 = 64; s2 > 0; s2 >>= 1) { if (tid < s2) tr[tid] += tr[tid + s2]; __syncthreads(); }
  const float inv = 1.0f / tr[0];
  __syncthreads();
  if (tid < S_) sm[tid] = expf(sm[tid] - mx) * inv;
  __syncthreads();
  const int d = tid * 2;
  const __half* eb = enc + (size_t)b * S_ * (2 * H_) + d;
  float c0 = 0.f, c1 = 0.f;
  for (int s0 = 0; s0 < S_; s0 += 8) {
    __half2 v[8];
#pragma unroll
    for (int i = 0; i < 8; ++i) v[i] = *(const __half2*)(eb + (size_t)(s0 + i) * (2 * H_));
#pragma unroll
    for (int i = 0; i < 8; ++i) {
      const float w = sm[s0 + i];
      c0 += w * __half2float(v[i].x);
      c1 += w * __half2float(v[i].y);
    }
  }
  *(float2*)(predin + (size_t)b * 3584 + H_ + d) = make_float2(c0, c1);
}

// =================== generic fp32 tiled GEMM (tables / br / q0) ==============
struct GB {
  const float* A; int lda;
  const __half* Ah;
  const float* W; int ldw;
  const float* bias;
  float* C; int ldc;
  __half* Ch;
  int M, N, K, act;
  const float *hf, *hb; int ldh;
  const float *mE, *tE, *pE;
  const int *mi, *ti, *pi;
};

template<int AMODE, int CMODE>
__global__ __launch_bounds__(256)
void gemm_k(GB g0, GB g1)
{
  GB g = blockIdx.z ? g1 : g0;
  const int m0 = blockIdx.y * 64, n0 = blockIdx.x * 64;
  if (m0 >= g.M || n0 >= g.N) return;
  __shared__ float As[32][68];
  __shared__ float Ws[32][68];
  const int tid = threadIdx.x, tx = tid & 15, ty = tid >> 4;
  const int lm = tid >> 3, lk = (tid & 7) << 2;
  float acc[4][4] = {};
  float4 av[2], wv[2], av2[2], wv2[2];

  auto load_tile = [&](int k0, float4 (&AV)[2], float4 (&WV)[2]) {
#pragma unroll
    for (int i = 0; i < 2; ++i) {
      const int row = lm + i * 32;
      const int kk = k0 + lk;
      if (AMODE == 0) {
        AV[i] = *(const float4*)(g.A + (size_t)(m0 + row) * g.lda + kk);
      } else if (AMODE == 4) {
        const __half* ap = g.Ah + (size_t)(m0 + row) * g.lda + kk;
        const __half2 h0 = *(const __half2*)ap;
        const __half2 h1 = *(const __half2*)(ap + 2);
        AV[i] = make_float4(__half2float(h0.x), __half2float(h0.y),
                            __half2float(h1.x), __half2float(h1.y));
      } else {
        const int mg = m0 + row; const float* sp; size_t o;
        if (kk < 1024)      { sp = g.hf; o = (size_t)mg * g.ldh + kk; }
        else if (kk < 2048) { sp = g.hb; o = (size_t)mg * g.ldh + kk - 1024; }
        else if (kk < 2176) { sp = g.mE; o = (size_t)g.mi[mg] * C_ + kk - 2048; }
        else if (kk < 2304) { sp = g.tE; o = (size_t)g.ti[mg] * C_ + kk - 2176; }
        else                { sp = g.pE; o = (size_t)g.pi[mg] * C_ + kk - 2304; }
        AV[i] = *(const float4*)(sp + o);
      }
      WV[i] = *(const float4*)(g.W + (size_t)(n0 + row) * g.ldw + kk);
    }
  };

  load_tile(0, av, wv);
  for (int k0 = 0; k0 < g.K; k0 += 32) {
    __syncthreads();
#pragma unroll
    for (int i = 0; i < 2; ++i) {
      const int row = lm + i * 32;
      As[lk + 0][row] = av[i].x; As[lk + 1][row] = av[i].y;
      As[lk + 2][row] = av[i].z; As[lk + 3][row] = av[i].w;
      Ws[lk + 0][row] = wv[i].x; Ws[lk + 1][row] = wv[i].y;
      Ws[lk + 2][row] = wv[i].z; Ws[lk + 3][row] = wv[i].w;
    }
    __syncthreads();
    if (k0 + 32 < g.K) load_tile(k0 + 32, av2, wv2);
#pragma unroll
    for (int k = 0; k < 32; ++k) {
      const float4 a4 = *(const float4*)&As[k][ty << 2];
      const float4 b4 = *(const float4*)&Ws[k][tx << 2];
      acc[0][0] += a4.x * b4.x; acc[0][1] += a4.x * b4.y; acc[0][2] += a4.x * b4.z; acc[0][3] += a4.x * b4.w;
      acc[1][0] += a4.y * b4.x; acc[1][1] += a4.y * b4.y; acc[1][2] += a4.y * b4.z; acc[1][3] += a4.y * b4.w;
      acc[2][0] += a4.z * b4.x; acc[2][1] += a4.z * b4.y; acc[2][2] += a4.z * b4.z; acc[2][3] += a4.z * b4.w;
      acc[3][0] += a4.w * b4.x; acc[3][1] += a4.w * b4.y; acc[3][2] += a4.w * b4.z; acc[3][3] += a4.w * b4.w;
    }
#pragma unroll
    for (int i = 0; i < 2; ++i) { av[i] = av2[i]; wv[i] = wv2[i]; }
  }
  const int n = n0 + (tx << 2);
  float4 bb = make_float4(0.f, 0.f, 0.f, 0.f);
  if (g.bias) bb = *(const float4*)(g.bias + n);
#pragma unroll
  for (int i = 0; i < 4; ++i) {
    const int m = m0 + (ty << 2) + i;
    float4 v = make_float4(acc[i][0] + bb.x, acc[i][1] + bb.y, acc[i][2] + bb.z, acc[i][3] + bb.w);
    if (CMODE == 0) {
      if (g.act) { v.x = tanhf(v.x); v.y = tanhf(v.y); v.z = tanhf(v.z); v.w = tanhf(v.w); }
      *(float4*)(g.C + (size_t)m * g.ldc + n) = v;
    } else {
      __half2* cp = (__half2*)(g.Ch + (size_t)m * g.ldc + n);
      cp[0] = __floats2half2_rn(v.x, v.y);
      cp[1] = __floats2half2_rn(v.z, v.w);
    }
  }
}

// =================== misc ===================
__global__ void zero_k(float* __restrict__ p, int n)
{
  const int i = blockIdx.x * 256 + threadIdx.x;
  if (i < n) p[i] = 0.0f;
}

__global__ void sentinel_k(float* out, float v) { out[threadIdx.x] = v; }

// =================== host orchestration ===================
extern "C" void kernel_launch(void* const* d_in, const int* in_sizes, int n_in,
                              void* d_out, int out_size, void* d_ws, size_t ws_size,
                              hipStream_t stream)
{
  const int*   src        = (const int*)d_in[0];
  const int*   tgt        = (const int*)d_in[1];
  const int*   mode_idx   = (const int*)d_in[2];
  const int*   tense_idx  = (const int*)d_in[3];
  const int*   person_idx = (const int*)d_in[4];
  const float* enc_emb    = (const float*)d_in[5];
  const float* eWih_f     = (const float*)d_in[6];
  const float* eWhh_f     = (const float*)d_in[7];
  const float* ebih_f     = (const float*)d_in[8];
  const float* ebhh_f     = (const float*)d_in[9];
  const float* eWih_b     = (const float*)d_in[10];
  const float* eWhh_b     = (const float*)d_in[11];
  const float* ebih_b     = (const float*)d_in[12];
  const float* ebhh_b     = (const float*)d_in[13];
  const float* Wa         = (const float*)d_in[14];
  const float* va         = (const float*)d_in[15];
  const float* dec_emb    = (const float*)d_in[16];
  const float* dWih       = (const float*)d_in[17];
  const float* dWhh       = (const float*)d_in[18];
  const float* dbih       = (const float*)d_in[19];
  const float* dbhh       = (const float*)d_in[20];
  const float* Wfc        = (const float*)d_in[21];
  const float* bfc        = (const float*)d_in[22];
  const float* mode_E     = (const float*)d_in[23];
  const float* tense_E    = (const float*)d_in[24];
  const float* person_E   = (const float*)d_in[25];
  const float* Wbr        = (const float*)d_in[26];
  const float* bbr        = (const float*)d_in[27];
  float* out = (float*)d_out;

  // ---- workspace carve (~251 MB; proven >= 268 MB) ----
  char* base = (char*)d_ws;
  size_t off = 0;
  auto alloc = [&](size_t bytes) { char* r = base + off; off = (off + bytes + 255) & ~(size_t)255; return r; };
  __half* enc_out = (__half*)alloc(2ull * B_ * S_ * 2 * H_);   // 100.7 MB
  __half* proj    = (__half*)alloc(2ull * B_ * S_ * H_);       // 50.3 MB
  short* whh_hi = (short*)alloc(2ull * 2 * 3 * H_ * H_);       // 12.6 MB
  short* whh_lo = (short*)alloc(2ull * 2 * 3 * H_ * H_);
  short* dpl_hi = (short*)alloc(2ull * 3 * H_ * 3072);         // 18.9 MB
  short* dpl_lo = (short*)alloc(2ull * 3 * H_ * 3072);
  short* fc_hi  = (short*)alloc(2ull * V_ * 3584);             // 1.8 MB
  short* fc_lo  = (short*)alloc(2ull * V_ * 3584);
  short* qa_hi  = (short*)alloc(2ull * H_ * H_);               // 2.1 MB
  short* qa_lo  = (short*)alloc(2ull * H_ * H_);
  __half* wae_hi = (__half*)alloc(2ull * H_ * 2048);           // 4.2 MB
  __half* wae_lo = (__half*)alloc(2ull * H_ * 2048);
  float* Gi_f  = (float*)alloc(4ull * V_ * 3 * H_);
  float* Gi_b  = (float*)alloc(4ull * V_ * 3 * H_);
  float* Gd    = (float*)alloc(4ull * V_ * 3 * H_);
  float* hfA   = (float*)alloc(4ull * B_ * H_);
  float* hfB   = (float*)alloc(4ull * B_ * H_);
  float* hbA   = (float*)alloc(4ull * B_ * H_);
  float* hbB   = (float*)alloc(4ull * B_ * H_);
  float* h_d0  = (float*)alloc(4ull * B_ * H_);
  float* h_d1  = (float*)alloc(4ull * B_ * H_);
  float* q     = (float*)alloc(4ull * B_ * H_);
  float* predin = (float*)alloc(4ull * B_ * 3584);
  int*   tok   = (int*)alloc(4ull * B_);
  float* zero_buf = (float*)alloc(4ull * 1024);
  if (off > ws_size) {
    hipLaunchKernelGGL(sentinel_k, dim3(1), dim3(256), 0, stream, out,
                       1000.0f + (float)(ws_size >> 20));
    return;
  }

  hipLaunchKernelGGL(zero_k, dim3(4), dim3(256), 0, stream, zero_buf, 1024);

  // ---- weight splits ----
  {
    const int n = 3 * H_ * H_;
    hipLaunchKernelGGL(wsplit_k, dim3((2 * n) / 256), dim3(256), 0, stream,
                       eWhh_f, eWhh_b, whh_hi, whh_lo, n);
    int tot = 3 * H_ * 2048;
    hipLaunchKernelGGL(split_plane_k, dim3((tot + 255) / 256), dim3(256), 0, stream,
                       dWih, 2560, 512, dpl_hi, dpl_lo, 3072, 0, tot, 2048);
    tot = 3 * H_ * 1024;
    hipLaunchKernelGGL(split_plane_k, dim3((tot + 255) / 256), dim3(256), 0, stream,
                       dWhh, 1024, 0, dpl_hi, dpl_lo, 3072, 2048, tot, 1024);
    tot = V_ * 3584;
    hipLaunchKernelGGL(split_plane_k, dim3((tot + 255) / 256), dim3(256), 0, stream,
                       Wfc, 3584, 0, fc_hi, fc_lo, 3584, 0, tot, 3584);
    tot = H_ * 1024;
    hipLaunchKernelGGL(split_plane_k, dim3((tot + 255) / 256), dim3(256), 0, stream,
                       Wa, 3 * H_, 0, qa_hi, qa_lo, 1024, 0, tot, 1024);
    tot = H_ * 2048;
    hipLaunchKernelGGL(split_plane_h_k, dim3((tot + 255) / 256), dim3(256), 0, stream,
                       Wa, 3 * H_, 1024, wae_hi, wae_lo, 2048, tot, 2048);
  }

  GB Z{};

  // ---- token tables ----
  {
    GB t0 = Z, t1 = Z;
    t0.A = enc_emb; t0.lda = E_; t0.W = eWih_f; t0.ldw = E_;
    t0.C = Gi_f; t0.ldc = 3 * H_; t0.M = V_; t0.N = 3 * H_; t0.K = E_;
    t1 = t0; t1.W = eWih_b; t1.C = Gi_b;
    hipLaunchKernelGGL((gemm_k<0, 0>), dim3(48, 4, 2), dim3(256), 0, stream, t0, t1);
    GB t2 = Z;
    t2.A = dec_emb; t2.lda = E_; t2.W = dWih; t2.ldw = 2560;
    t2.C = Gd; t2.ldc = 3 * H_; t2.M = V_; t2.N = 3 * H_; t2.K = E_;
    hipLaunchKernelGGL((gemm_k<0, 0>), dim3(48, 4, 1), dim3(256), 0, stream, t2, t2);
  }

  // ---- encoder: 96 MFMA steps ----
  for (int t = 0; t < S_; ++t) {
    EM em{};
    em.gidx = src; em.goff0 = t; em.goff1 = S_ - 1 - t;
    em.Gt0 = Gi_f; em.Gt1 = Gi_b;
    if (t == 0) { em.h0 = zero_buf; em.h1 = zero_buf; em.ldh = 0; }
    else if (t & 1) { em.h0 = hfA; em.h1 = hbA; em.ldh = H_; }
    else            { em.h0 = hfB; em.h1 = hbB; em.ldh = H_; }
    em.whi = whh_hi; em.wlo = whh_lo;
    em.bih0 = ebih_f; em.bih1 = ebih_b; em.bhh0 = ebhh_f; em.bhh1 = ebhh_b;
    if (t & 1) { em.d0 = hfB; em.d1 = hbB; } else { em.d0 = hfA; em.d1 = hbA; }
    em.e0 = enc_out + (size_t)t * 2 * H_;
    em.e1 = enc_out + (size_t)(S_ - 1 - t) * 2 * H_ + H_;
    em.lde = S_ * 2 * H_;
    hipLaunchKernelGGL(enc_mfma_k, dim3(512), dim3(256), 0, stream, em);
  }
  float* hf_fin = hfB;   // t=95 (odd) wrote hfB/hbB
  float* hb_fin = hbB;

  // ---- enc_proj via fp16 MFMA (m-reuse, B L1-shared, 3072 blocks) ----
  hipLaunchKernelGGL(proj_mfma_k, dim3(3072), dim3(256), 0, stream,
                     enc_out, wae_hi, wae_lo, proj);

  // ---- dec_h0 ----
  {
    GB br = Z;
    br.W = Wbr; br.ldw = 2432; br.bias = bbr; br.C = h_d0; br.ldc = H_;
    br.M = B_; br.N = H_; br.K = 2432; br.act = 1;
    br.hf = hf_fin; br.hb = hb_fin; br.ldh = H_;
    br.mE = mode_E; br.tE = tense_E; br.pE = person_E;
    br.mi = mode_idx; br.ti = tense_idx; br.pi = person_idx;
    hipLaunchKernelGGL((gemm_k<2, 0>), dim3(16, 4, 1), dim3(256), 0, stream, br, br);
  }

  // ---- q(0) ----
  {
    GB qa = Z;
    qa.A = h_d0; qa.lda = H_; qa.W = Wa; qa.ldw = 3 * H_; qa.C = q; qa.ldc = H_;
    qa.M = B_; qa.N = H_; qa.K = H_;
    hipLaunchKernelGGL((gemm_k<0, 0>), dim3(16, 4, 1), dim3(256), 0, stream, qa, qa);
  }

  // ---- decoder: 39 steps x (attnctx, dec_mfma, prqa_mfma) ----
  float* hd[2] = { h_d0, h_d1 };
  for (int t = 0; t < T_ - 1; ++t) {
    hipLaunchKernelGGL(attnctx_k, dim3(B_), dim3(1024), 0, stream,
                       out, tgt, q, proj, va, src, dec_emb, enc_out, predin, tok, t);

    DM dm{};
    dm.predin = predin;
    dm.h = hd[t & 1];
    dm.tok = tok; dm.Gd = Gd;
    dm.whi = dpl_hi; dm.wlo = dpl_lo;
    dm.bih = dbih; dm.bhh = dbhh;
    dm.d = hd[(t + 1) & 1];
    dm.predout = predin;
    hipLaunchKernelGGL(dec_mfma_k, dim3(256), dim3(768), 0, stream, dm);

    hipLaunchKernelGGL(prqa_mfma_k, dim3(512), dim3(256), 0, stream,
                       predin, fc_hi, fc_lo, bfc, hd[(t + 1) & 1], qa_hi, qa_lo,
                       out + (size_t)t * V_, q);
  }
}